// Round 21
// baseline (137.768 us; speedup 1.0000x reference)
//
#include <hip/hip_runtime.h>
#include <hip/hip_bf16.h>
#include <stdint.h>

// Problem constants
#define BB 64      // batch
#define JJ 2048    // input capsules
#define DI 16      // input dim
#define CC 32      // output capsules
#define OO 32      // output dim
#define CO 1024    // CC*OO
#define TJ 16      // j per block
#define NJT 128    // JJ/TJ

static const size_t W2_BYTES = (size_t)CC * JJ * OO * DI * 2;  // 64 MB
static const size_t X3_BYTES = (size_t)BB * JJ * DI * 2;       // 4 MB

typedef _Float16 f16x4 __attribute__((ext_vector_type(4)));
typedef float    f32x4 __attribute__((ext_vector_type(4)));
typedef unsigned short ushort_t;

// __has_builtin on amdgcn builtins is false in the host pass (R7 lesson).
#if defined(__HIP_DEVICE_COMPILE__)
# if __has_builtin(__builtin_amdgcn_mfma_f32_16x16x16f16)
#  define MFMA16(a, b, c) __builtin_amdgcn_mfma_f32_16x16x16f16((a), (b), (c), 0, 0, 0)
# else
#  define MFMA16(a, b, c) __builtin_amdgcn_mfma_f32_16x16x16_f16((a), (b), (c), 0, 0, 0)
# endif
# define SCHED_FENCE() __builtin_amdgcn_sched_barrier(0)
#else
# define MFMA16(a, b, c) (c)
# define SCHED_FENCE()
#endif

#if __has_attribute(amdgpu_waves_per_eu)
# define WAVES4 __attribute__((amdgpu_waves_per_eu(4, 4)))
#else
# define WAVES4
#endif

union Pack2 { unsigned u; _Float16 h[2]; };

__device__ __forceinline__ ushort_t f2bf(float f) {   // RNE f32 -> bf16
  unsigned u = __float_as_uint(f);
  u += 0x7FFFu + ((u >> 16) & 1u);
  return (ushort_t)(u >> 16);
}
__device__ __forceinline__ float bf2f(ushort_t b) {
  return __uint_as_float(((unsigned)b) << 16);
}

// x [b][j][i] f32 -> X3 f16 in B-fragment order (B = x, cols = b, k = i).
__global__ __launch_bounds__(256) void prep_x(const float* __restrict__ X,
                                              uint2* __restrict__ X3) {
  const unsigned T = blockIdx.x * 256 + threadIdx.x;   // 524288
  const int l = T & 63, bt = (T >> 6) & 1, j = (T >> 7) & 2047, bq = (int)(T >> 18);
  const int b = bq * 32 + bt * 16 + (l & 15);
  const float4 src = ((const float4*)X)[((size_t)b * JJ + j) * 4 + (l >> 4)];
  Pack2 a, bb;
  a.h[0] = (_Float16)src.x; a.h[1] = (_Float16)src.y;
  bb.h[0] = (_Float16)src.z; bb.h[1] = (_Float16)src.w;
  X3[T] = make_uint2(a.u, bb.u);
}

// R21 pass 0: convert + route fused (R20) with FIRE-AND-FORGET W2 stores.
// R20 bug: stores were issued before stage(jj+2), so the top-of-loop vmcnt(4)
// forced the 4 HBM store-acks to retire EVERY iteration (~40 us). Now each
// body issues: ds_read -> lgkmcnt(0) -> stage(jj+2) -> cvt -> stores -> MFMA,
// and the top wait leaves stores in flight:
//   bq==0: ops issued after stage(jj) = stores(jj-2)+stage(jj+1)+stores(jj-1)
//          -> vmcnt(12) steady (8 at jj==1 and jj==TJ-1; 4 at jj==0)
//   bq==1 (no stores): vmcnt(4) (0 at jj==TJ-1)
__global__ __launch_bounds__(1024, 4) WAVES4 void route_conv(
    const uint4* __restrict__ X3, const float* __restrict__ Wf,
    uint2* __restrict__ W2out, ushort_t* __restrict__ partial)
{
  __shared__ uint4 wbuf32[2][4096];  // 2 x 64KB f32 A-frag slabs
  __shared__ uint4 xbuf[1024];       // 16KB x B-frags

  const int jt   = blockIdx.x & (NJT - 1);
  const int bq   = blockIdx.x >> 7;
  const int tid  = threadIdx.x;
  const int w    = tid >> 6;
  const int lane = tid & 63;
  const int g    = lane >> 4;
  const int t    = lane & 15;

  // Wave-private f32 stage: instr r covers tile ct = w*4+r; 64 lanes' sources
  // are one contiguous 1KB row-block of W; dest = linear lane*16.
#define STAGEC(slot, jjv) do {                                                    \
    const int j_ = jt * TJ + (jjv);                                               \
    _Pragma("unroll")                                                             \
    for (int r_ = 0; r_ < 4; ++r_) {                                              \
      const int ct_ = w * 4 + r_;                                                 \
      const uint4* sp_ = (const uint4*)Wf                                         \
          + ((size_t)(ct_ >> 1) * JJ + j_) * 128 + (ct_ & 1) * 64                 \
          + (lane & 15) * 4 + (lane >> 4);                                        \
      uint4* dp_ = &wbuf32[slot][w * 256 + r_ * 64 + lane];                       \
      __builtin_amdgcn_global_load_lds(                                           \
          (const __attribute__((address_space(1))) void*)sp_,                     \
          (__attribute__((address_space(3))) void*)dp_, 16, 0, 0);                \
    }                                                                             \
  } while (0)

  // prologue: x B-frags + slabs 0,1
  {
    const uint4* xs = X3 + ((size_t)bq * JJ + jt * TJ) * 64 + tid;
    __builtin_amdgcn_global_load_lds(
        (const __attribute__((address_space(1))) void*)xs,
        (__attribute__((address_space(3))) void*)&xbuf[tid], 16, 0, 0);
  }
  STAGEC(0, 0);
  STAGEC(1, 1);
  asm volatile("s_waitcnt vmcnt(8)" ::: "memory");   // xbuf (oldest) landed
  SCHED_FENCE();
  __builtin_amdgcn_s_barrier();

  f32x4 acc[4][2];
#pragma unroll
  for (int k = 0; k < 4; ++k)
#pragma unroll
    for (int bt = 0; bt < 2; ++bt) acc[k][bt] = f32x4{0.f, 0.f, 0.f, 0.f};

  for (int jj = 0; jj < TJ; ++jj) {
    const int bcur = jj & 1;
    // top wait: force stage(jj) complete, keep stores + stage(jj+1) in flight
    if (bq == 0) {
      if (jj == 0)                      asm volatile("s_waitcnt vmcnt(4)"  ::: "memory");
      else if (jj == 1 || jj == TJ - 1) asm volatile("s_waitcnt vmcnt(8)"  ::: "memory");
      else                              asm volatile("s_waitcnt vmcnt(12)" ::: "memory");
    } else {
      if (jj == TJ - 1) asm volatile("s_waitcnt vmcnt(0)" ::: "memory");
      else              asm volatile("s_waitcnt vmcnt(4)" ::: "memory");
    }
    SCHED_FENCE();

    // ds reads: x B-frags + this wave's f32 A-frags
    const uint2* xb2 = (const uint2*)xbuf;
    f16x4 bf[2];
#pragma unroll
    for (int bt = 0; bt < 2; ++bt)
      bf[bt] = __builtin_bit_cast(f16x4, xb2[(jj * 2 + bt) * 64 + lane]);

    const f32x4* wr = (const f32x4*)wbuf32[bcur];
    f32x4 a32[4];
#pragma unroll
    for (int k = 0; k < 4; ++k) a32[k] = wr[w * 256 + k * 64 + lane];

    // reads in regs -> safe to overwrite this slot; issue next stage NOW
    asm volatile("s_waitcnt lgkmcnt(0)" ::: "memory");
    SCHED_FENCE();
    if (jj + 2 < TJ) STAGEC(bcur, jj + 2);
    SCHED_FENCE();

    // cvt f32 -> f16 fragments
    f16x4 af[4];
#pragma unroll
    for (int k = 0; k < 4; ++k) {
      af[k][0] = (_Float16)a32[k][0]; af[k][1] = (_Float16)a32[k][1];
      af[k][2] = (_Float16)a32[k][2]; af[k][3] = (_Float16)a32[k][3];
    }

    // fire-and-forget W2 stores (bq==0 only) — never drained mid-loop
    if (bq == 0) {
      const size_t wbase = (size_t)(jt * TJ + jj) * 4096;
#pragma unroll
      for (int k = 0; k < 4; ++k) {
        Pack2 p0, p1;
        p0.h[0] = af[k][0]; p0.h[1] = af[k][1];
        p1.h[0] = af[k][2]; p1.h[1] = af[k][3];
        W2out[wbase + (w * 4 + k) * 64 + lane] = make_uint2(p0.u, p1.u);
      }
    }

#pragma unroll
    for (int k = 0; k < 4; ++k)
#pragma unroll
      for (int bt = 0; bt < 2; ++bt)
        acc[k][bt] = MFMA16(af[k], bf[bt], acc[k][bt]);
  }
#undef STAGEC

  // uniform coef 1/32; bf16 partial store
#pragma unroll
  for (int k = 0; k < 4; ++k)
#pragma unroll
    for (int bt = 0; bt < 2; ++bt) {
      const int b  = bq * 32 + bt * 16 + t;
      const int co = (4 * w + k) * 16 + 4 * g;
      ushort4 v;
      v.x = f2bf(acc[k][bt][0] * 0.03125f);
      v.y = f2bf(acc[k][bt][1] * 0.03125f);
      v.z = f2bf(acc[k][bt][2] * 0.03125f);
      v.w = f2bf(acc[k][bt][3] * 0.03125f);
      *(ushort4*)(partial + ((size_t)jt * BB + b) * CO + co) = v;
    }
}

// R19 HAVE_V route (proven): wave-private f16 staging, no top barrier,
// 2 barriers/jj (logit, coef), parity-dbuf lbuf, bf16 partial.
__global__ __launch_bounds__(1024, 4) WAVES4 void route_v(
    const uint4* __restrict__ X3, const uint4* __restrict__ W2,
    const float* __restrict__ vsum, ushort_t* __restrict__ partial)
{
  __shared__ uint4 wbuf[4][2048];    // 4 x 32KB W slabs (A-frags)
  __shared__ uint4 xbuf[1024];       // 16KB x B-frags
  __shared__ float lbuf[2][32 * 33];

  const int jt   = blockIdx.x & (NJT - 1);
  const int bq   = blockIdx.x >> 7;
  const int tid  = threadIdx.x;
  const int w    = tid >> 6;
  const int lane = tid & 63;
  const int g    = lane >> 4;
  const int t    = lane & 15;

  unsigned vsh[2][2][2][2];   // [cc][bt][hh][rp]
#pragma unroll
  for (int cc = 0; cc < 2; ++cc)
#pragma unroll
    for (int bt = 0; bt < 2; ++bt)
#pragma unroll
      for (int hh = 0; hh < 2; ++hh)
#pragma unroll
        for (int rp = 0; rp < 2; ++rp) {
          const float* vp = vsum + (size_t)(bq * 32 + bt * 16 + t) * CO
                          + (2 * w + cc) * OO + hh * 16 + 4 * g + 2 * rp;
          Pack2 p; p.h[0] = (_Float16)vp[0]; p.h[1] = (_Float16)vp[1];
          vsh[cc][bt][hh][rp] = p.u;
        }
  asm volatile("s_waitcnt vmcnt(0)" ::: "memory");

  const uint4* wsrc = W2 + (size_t)jt * TJ * 2048;

#define STAGEW(bufidx, slab) do {                                                 \
    const uint4* sp_ = wsrc + (size_t)(slab) * 2048 + w * 128 + lane;             \
    uint4* dp_ = &wbuf[bufidx][w * 128 + lane];                                   \
    _Pragma("unroll")                                                             \
    for (int r_ = 0; r_ < 2; ++r_)                                                \
      __builtin_amdgcn_global_load_lds(                                           \
          (const __attribute__((address_space(1))) void*)(sp_ + r_ * 64),         \
          (__attribute__((address_space(3))) void*)(dp_ + r_ * 64), 16, 0, 0);    \
  } while (0)

  {
    const uint4* xs = X3 + ((size_t)bq * JJ + jt * TJ) * 64 + tid;
    __builtin_amdgcn_global_load_lds(
        (const __attribute__((address_space(1))) void*)xs,
        (__attribute__((address_space(3))) void*)&xbuf[tid], 16, 0, 0);
  }
  STAGEW(0, 0);
  STAGEW(1, 1);
  STAGEW(2, 2);
  asm volatile("s_waitcnt vmcnt(6)" ::: "memory");
  SCHED_FENCE();
  __builtin_amdgcn_s_barrier();

  f32x4 acc[4][2];
#pragma unroll
  for (int k = 0; k < 4; ++k)
#pragma unroll
    for (int bt = 0; bt < 2; ++bt) acc[k][bt] = f32x4{0.f, 0.f, 0.f, 0.f};

  for (int jj = 0; jj < TJ; ++jj) {
    const int bcur = jj & 3;
    if (jj < TJ - 2)       asm volatile("s_waitcnt vmcnt(4)" ::: "memory");
    else if (jj == TJ - 2) asm volatile("s_waitcnt vmcnt(2)" ::: "memory");
    else                   asm volatile("s_waitcnt vmcnt(0)" ::: "memory");
    SCHED_FENCE();
    if (jj + 3 < TJ) STAGEW((jj + 3) & 3, jj + 3);

    const uint2* wb2 = (const uint2*)wbuf[bcur];
    const uint2* xb2 = (const uint2*)xbuf;

    f16x4 bf[2];
#pragma unroll
    for (int bt = 0; bt < 2; ++bt)
      bf[bt] = __builtin_bit_cast(f16x4, xb2[(jj * 2 + bt) * 64 + lane]);
    f16x4 af[4];
#pragma unroll
    for (int k = 0; k < 4; ++k)
      af[k] = __builtin_bit_cast(f16x4, wb2[(w * 4 + k) * 64 + lane]);

    f32x4 uh[4][2];
#pragma unroll
    for (int k = 0; k < 4; ++k)
#pragma unroll
      for (int bt = 0; bt < 2; ++bt)
        uh[k][bt] = MFMA16(af[k], bf[bt], (f32x4{0.f, 0.f, 0.f, 0.f}));

    float lp[2][2];
#pragma unroll
    for (int cc = 0; cc < 2; ++cc)
#pragma unroll
      for (int bt = 0; bt < 2; ++bt) {
        float s = 0.f;
#pragma unroll
        for (int hh = 0; hh < 2; ++hh)
#pragma unroll
          for (int rp = 0; rp < 2; ++rp) {
            Pack2 p; p.u = vsh[cc][bt][hh][rp];
            s = fmaf(uh[2 * cc + hh][bt][2 * rp],     (float)p.h[0], s);
            s = fmaf(uh[2 * cc + hh][bt][2 * rp + 1], (float)p.h[1], s);
          }
        s += __shfl_xor(s, 16);
        s += __shfl_xor(s, 32);
        lp[cc][bt] = s;
      }
    {
      const float hi = (g & 1) ? lp[1][1] : lp[1][0];
      const float lo = (g & 1) ? lp[0][1] : lp[0][0];
      const float val = (g >> 1) ? hi : lo;
      lbuf[jj & 1][((g & 1) * 16 + t) * 33 + 2 * w + (g >> 1)] = val;
    }
    asm volatile("s_waitcnt lgkmcnt(0)" ::: "memory");
    SCHED_FENCE();
    __builtin_amdgcn_s_barrier();

    {
      const int row = 2 * w + (lane >> 5);
      const int cc2 = lane & 31;
      float e = __expf(lbuf[jj & 1][row * 33 + cc2]);
      float den = e;
      den += __shfl_xor(den, 1);  den += __shfl_xor(den, 2);
      den += __shfl_xor(den, 4);  den += __shfl_xor(den, 8);
      den += __shfl_xor(den, 16);
      lbuf[jj & 1][row * 33 + cc2] = e / den;
    }
    asm volatile("s_waitcnt lgkmcnt(0)" ::: "memory");
    SCHED_FENCE();
    __builtin_amdgcn_s_barrier();

    float cf[2][2];
#pragma unroll
    for (int cc = 0; cc < 2; ++cc)
#pragma unroll
      for (int bt = 0; bt < 2; ++bt)
        cf[cc][bt] = lbuf[jj & 1][(bt * 16 + t) * 33 + 2 * w + cc];
#pragma unroll
    for (int k = 0; k < 4; ++k)
#pragma unroll
      for (int bt = 0; bt < 2; ++bt)
#pragma unroll
        for (int r = 0; r < 4; ++r)
          acc[k][bt][r] = fmaf(cf[k >> 1][bt], uh[k][bt][r], acc[k][bt][r]);
  }
#undef STAGEW

#pragma unroll
  for (int k = 0; k < 4; ++k)
#pragma unroll
    for (int bt = 0; bt < 2; ++bt) {
      const int b  = bq * 32 + bt * 16 + t;
      const int co = (4 * w + k) * 16 + 4 * g;
      ushort4 v;
      v.x = f2bf(acc[k][bt][0]);
      v.y = f2bf(acc[k][bt][1]);
      v.z = f2bf(acc[k][bt][2]);
      v.w = f2bf(acc[k][bt][3]);
      *(ushort4*)(partial + ((size_t)jt * BB + b) * CO + co) = v;
    }
}

// ---------------- f32 fallback route (proven R2/R4 path) ----------------
template<bool HAVE_V>
__global__ __launch_bounds__(256, 1) void route_f32(
    const float* __restrict__ X, const float* __restrict__ W,
    const float* __restrict__ vsum, float* __restrict__ partial)
{
  const int jt   = blockIdx.x & 63;
  const int bq   = blockIdx.x >> 6;
  const int tid  = threadIdx.x;
  const int wave = tid >> 6;
  const int lane = tid & 63;
  const int c    = lane & 31;
  const int o0   = (lane >> 5) << 4;
  const int b0   = bq * 16 + wave * 4;

  float acc[4][16];
#pragma unroll
  for (int bl = 0; bl < 4; ++bl)
#pragma unroll
    for (int ol = 0; ol < 16; ++ol) acc[bl][ol] = 0.f;

  const float* wbase = W + ((size_t)c * JJ * OO + (size_t)o0) * DI;

  for (int jj = 0; jj < 32; ++jj) {
    const int j = jt * 32 + jj;
    float xf[4][16];
#pragma unroll
    for (int bl = 0; bl < 4; ++bl) {
      const float4* xpt = (const float4*)(X + ((size_t)(b0 + bl) * JJ + j) * DI);
#pragma unroll
      for (int q = 0; q < 4; ++q) {
        float4 x4 = xpt[q];
        xf[bl][4*q+0] = x4.x; xf[bl][4*q+1] = x4.y;
        xf[bl][4*q+2] = x4.z; xf[bl][4*q+3] = x4.w;
      }
    }
    const float4* wp = (const float4*)(wbase + (size_t)j * OO * DI);
    float tv[4][16];
#pragma unroll
    for (int ol = 0; ol < 16; ++ol) {
      float wf[16];
#pragma unroll
      for (int q = 0; q < 4; ++q) {
        float4 w4 = wp[4*ol + q];
        wf[4*q+0] = w4.x; wf[4*q+1] = w4.y;
        wf[4*q+2] = w4.z; wf[4*q+3] = w4.w;
      }
#pragma unroll
      for (int bl = 0; bl < 4; ++bl) {
        float tt = 0.f;
#pragma unroll
        for (int i = 0; i < 16; ++i) tt = fmaf(wf[i], xf[bl][i], tt);
        if (!HAVE_V) acc[bl][ol] += tt;
        else         tv[bl][ol] = tt;
      }
    }
    if (HAVE_V) {
#pragma unroll
      for (int bl = 0; bl < 4; ++bl) {
        float dsum = 0.f;
        const float4* vp = (const float4*)(vsum + (size_t)(b0 + bl) * CO + c * OO + o0);
#pragma unroll
        for (int q = 0; q < 4; ++q) {
          float4 v4 = vp[q];
          dsum = fmaf(v4.x, tv[bl][4*q+0], dsum);
          dsum = fmaf(v4.y, tv[bl][4*q+1], dsum);
          dsum = fmaf(v4.z, tv[bl][4*q+2], dsum);
          dsum = fmaf(v4.w, tv[bl][4*q+3], dsum);
        }
        dsum += __shfl_xor(dsum, 32);
        float mm = dsum;
#pragma unroll
        for (int s = 16; s >= 1; s >>= 1) mm = fmaxf(mm, __shfl_xor(mm, s));
        float e = __expf(dsum - mm);
        float den = e;
#pragma unroll
        for (int s = 16; s >= 1; s >>= 1) den += __shfl_xor(den, s);
        float coef = e / den;
#pragma unroll
        for (int ol = 0; ol < 16; ++ol)
          acc[bl][ol] = fmaf(coef, tv[bl][ol], acc[bl][ol]);
      }
    }
  }
  const float cs = HAVE_V ? 1.f : 0.03125f;
#pragma unroll
  for (int bl = 0; bl < 4; ++bl) {
    float* pp = partial + ((size_t)jt * BB + (b0 + bl)) * CO + c * OO + o0;
#pragma unroll
    for (int q = 0; q < 4; ++q) {
      float4 w4 = make_float4(acc[bl][4*q+0]*cs, acc[bl][4*q+1]*cs,
                              acc[bl][4*q+2]*cs, acc[bl][4*q+3]*cs);
      ((float4*)pp)[q] = w4;
    }
  }
}

// Sum NJT bf16 j-tile partials -> s[b,c,o]; squash over o; vsum / out.
__global__ __launch_bounds__(256, 1) void reduce_squash_bf(
    const ushort_t* __restrict__ partial, float* __restrict__ vsum,
    float* __restrict__ out, int mode)   // 0: vsum = v; 1: vsum += v; 2: out = v
{
  const int idx = blockIdx.x * 256 + threadIdx.x;   // = b*CO + c*OO + o
  float s0 = 0.f, s1 = 0.f, s2 = 0.f, s3 = 0.f;
#pragma unroll 4
  for (int nt = 0; nt < NJT; nt += 4) {
    s0 += bf2f(partial[(size_t)(nt + 0) * (BB * CO) + idx]);
    s1 += bf2f(partial[(size_t)(nt + 1) * (BB * CO) + idx]);
    s2 += bf2f(partial[(size_t)(nt + 2) * (BB * CO) + idx]);
    s3 += bf2f(partial[(size_t)(nt + 3) * (BB * CO) + idx]);
  }
  float s = (s0 + s1) + (s2 + s3);
  float s2m = s * s;
#pragma unroll
  for (int mk = 16; mk >= 1; mk >>= 1) s2m += __shfl_xor(s2m, mk);
  float scale = s2m / ((1.f + s2m) * sqrtf(s2m + 1e-7f));
  float v = scale * s;
  if (mode == 2)      out[idx] = v;
  else if (mode == 1) vsum[idx] += v;
  else                vsum[idx] = v;
}

// f32 reduce for the fallback path
template<int NJTR>
__global__ __launch_bounds__(256, 1) void reduce_squash(
    const float* __restrict__ partial, float* __restrict__ vsum,
    float* __restrict__ out, int mode)
{
  const int idx = blockIdx.x * 256 + threadIdx.x;
  float s0 = 0.f, s1 = 0.f, s2 = 0.f, s3 = 0.f;
#pragma unroll 4
  for (int nt = 0; nt < NJTR; nt += 4) {
    s0 += partial[(size_t)(nt + 0) * (BB * CO) + idx];
    s1 += partial[(size_t)(nt + 1) * (BB * CO) + idx];
    s2 += partial[(size_t)(nt + 2) * (BB * CO) + idx];
    s3 += partial[(size_t)(nt + 3) * (BB * CO) + idx];
  }
  float s = (s0 + s1) + (s2 + s3);
  float s2m = s * s;
#pragma unroll
  for (int mk = 16; mk >= 1; mk >>= 1) s2m += __shfl_xor(s2m, mk);
  float scale = s2m / ((1.f + s2m) * sqrtf(s2m + 1e-7f));
  float v = scale * s;
  if (mode == 2)      out[idx] = v;
  else if (mode == 1) vsum[idx] += v;
  else                vsum[idx] = v;
}

static void run_mfma(const float* X, const float* W, float* out,
                     void* d_ws, hipStream_t stream)
{
  uint2* W2         = (uint2*)d_ws;
  uint2* X3         = (uint2*)((char*)d_ws + W2_BYTES);
  ushort_t* partial = (ushort_t*)((char*)d_ws + W2_BYTES + X3_BYTES);
  float* vsum       = (float*)((char*)d_ws + W2_BYTES + X3_BYTES
                               + (size_t)NJT * BB * CO * 2);
  const int grid  = NJT * 2;         // 256 blocks of 1024
  const int rgrid = BB * CO / 256;

  prep_x<<<2048, 256, 0, stream>>>(X, X3);

  // pass 0 converts W inline and emits W2 for passes 1-2 (prep_w deleted)
  route_conv<<<grid, 1024, 0, stream>>>((const uint4*)X3, W, W2, partial);
  reduce_squash_bf<<<rgrid, 256, 0, stream>>>(partial, vsum, nullptr, 0);

  route_v<<<grid, 1024, 0, stream>>>((const uint4*)X3, (const uint4*)W2, vsum, partial);
  reduce_squash_bf<<<rgrid, 256, 0, stream>>>(partial, vsum, nullptr, 1);

  route_v<<<grid, 1024, 0, stream>>>((const uint4*)X3, (const uint4*)W2, vsum, partial);
  reduce_squash_bf<<<rgrid, 256, 0, stream>>>(partial, vsum, out, 2);
}

static void run_f32_fallback(const float* X, const float* W, float* out,
                             void* d_ws, hipStream_t stream)
{
  float* partial = (float*)d_ws;
  float* vsum    = partial + (size_t)64 * BB * CO;
  const int grid  = 64 * 4;
  const int rgrid = BB * CO / 256;

  route_f32<false><<<grid, 256, 0, stream>>>(X, W, nullptr, partial);
  reduce_squash<64><<<rgrid, 256, 0, stream>>>(partial, vsum, nullptr, 0);
  route_f32<true><<<grid, 256, 0, stream>>>(X, W, vsum, partial);
  reduce_squash<64><<<rgrid, 256, 0, stream>>>(partial, vsum, nullptr, 1);
  route_f32<true><<<grid, 256, 0, stream>>>(X, W, vsum, partial);
  reduce_squash<64><<<rgrid, 256, 0, stream>>>(partial, vsum, out, 2);
}

extern "C" void kernel_launch(void* const* d_in, const int* in_sizes, int n_in,
                              void* d_out, int out_size, void* d_ws, size_t ws_size,
                              hipStream_t stream) {
  (void)in_sizes; (void)n_in; (void)out_size;
  const float* X = (const float*)d_in[0];   // x [64,2048,16] f32
  const float* W = (const float*)d_in[1];   // W [32,2048,32,16] f32
  float* out = (float*)d_out;               // v [64,32,32] f32

  const size_t need = W2_BYTES + X3_BYTES
                    + (size_t)NJT * BB * CO * 2 + (size_t)BB * CO * 4;
  if (ws_size >= need) run_mfma(X, W, out, d_ws, stream);
  else                 run_f32_fallback(X, W, out, d_ws, stream);
}